// Round 5
// baseline (379.495 us; speedup 1.0000x reference)
//
#include <hip/hip_runtime.h>
#include <hip/hip_bf16.h>
#include <stdint.h>

#define NB 2
#define NH 16
#define LT 2048
#define LS 2048
#define DIM 1024
#define HD 64

typedef __attribute__((ext_vector_type(4))) float f32x4;
typedef __attribute__((ext_vector_type(8))) short short8;
typedef __attribute__((ext_vector_type(4))) short short4v;
typedef __attribute__((ext_vector_type(2))) short short2v;

__device__ __forceinline__ short f2bf(float f) {
  __hip_bfloat16 h = __float2bfloat16(f);
  return *reinterpret_cast<short*>(&h);
}

// XOR-swizzled byte offset within a [rows][128B] LDS tile (T2 / G4 pattern)
__device__ __forceinline__ int swz(int row, int bc) { return (row << 7) + (bc ^ ((row & 7) << 4)); }

// ---- weight transpose+cast: W[K][N] fp32 -> Wt[N][K] bf16 (4 weights) ----
__global__ __launch_bounds__(256) void wt_kernel(const float* __restrict__ Wq, const float* __restrict__ Wk,
                                                 const float* __restrict__ Wv, const float* __restrict__ Wo,
                                                 short* __restrict__ wt) {
  __shared__ float tile[64][68];
  const int bid = blockIdx.x;
  const int widx = bid >> 8;
  const int rem = bid & 255;
  const int kt = rem >> 4, nt = rem & 15;
  const float* W = (widx == 0) ? Wq : (widx == 1) ? Wk : (widx == 2) ? Wv : Wo;
  const int tid = threadIdx.x;
  {
    const int r = tid >> 2, c0 = (tid & 3) << 4;
    const float* src = W + (size_t)(kt * 64 + r) * DIM + nt * 64 + c0;
#pragma unroll
    for (int j = 0; j < 4; ++j)
      *reinterpret_cast<f32x4*>(&tile[r][c0 + 4 * j]) = *reinterpret_cast<const f32x4*>(src + 4 * j);
  }
  __syncthreads();
  {
    const int n = tid >> 2, k0 = (tid & 3) << 4;
    short outv[16];
#pragma unroll
    for (int j = 0; j < 16; ++j) outv[j] = f2bf(tile[k0 + j][n]);
    short* dst = wt + (size_t)widx * DIM * DIM + (size_t)(nt * 64 + n) * DIM + kt * 64 + k0;
    *reinterpret_cast<short8*>(dst) = *reinterpret_cast<short8*>(&outv[0]);
    *reinterpret_cast<short8*>(dst + 8) = *reinterpret_cast<short8*>(&outv[8]);
  }
}

// ---- GEMM: C = A[4096][1024] * Bt[N=1024][K=1024]^T (Bt bf16, pre-transposed)
template <int MODE>
__global__ __launch_bounds__(256) void gemm_kernel(const void* __restrict__ Aptr, const short* __restrict__ Bt,
                                                   void* __restrict__ outp, short* __restrict__ out_bf) {
  __shared__ short a_lds[128][40];
  __shared__ short b_lds[128][40];
  const int bm = blockIdx.x & 31, bn = blockIdx.x >> 5;
  const int tid = threadIdx.x;
  const int lane = tid & 63, w = tid >> 6;
  const int wr = w >> 1, wc = w & 1;
  const int lm = lane & 15, g8 = (lane >> 4) << 3;
  f32x4 acc[4][4];
#pragma unroll
  for (int i = 0; i < 4; ++i)
#pragma unroll
    for (int j = 0; j < 4; ++j) acc[i][j] = (f32x4){0.f, 0.f, 0.f, 0.f};

  const int sr = tid >> 1, sc0 = (tid & 1) << 4;
  for (int k0 = 0; k0 < 1024; k0 += 32) {
    __syncthreads();
    short abuf[16];
    if (MODE == 2) {
      const short* src = (const short*)Aptr + (size_t)(bm * 128 + sr) * 1024 + k0 + sc0;
      *reinterpret_cast<short8*>(&abuf[0]) = *reinterpret_cast<const short8*>(src);
      *reinterpret_cast<short8*>(&abuf[8]) = *reinterpret_cast<const short8*>(src + 8);
    } else {
      const float* src = (const float*)Aptr + (size_t)(bm * 128 + sr) * 1024 + k0 + sc0;
#pragma unroll
      for (int j = 0; j < 16; ++j) abuf[j] = f2bf(src[j]);
    }
    *reinterpret_cast<short8*>(&a_lds[sr][sc0]) = *reinterpret_cast<short8*>(&abuf[0]);
    *reinterpret_cast<short8*>(&a_lds[sr][sc0 + 8]) = *reinterpret_cast<short8*>(&abuf[8]);
    const short* bsrc = Bt + (size_t)(bn * 128 + sr) * 1024 + k0 + sc0;
    *reinterpret_cast<short8*>(&b_lds[sr][sc0]) = *reinterpret_cast<const short8*>(bsrc);
    *reinterpret_cast<short8*>(&b_lds[sr][sc0 + 8]) = *reinterpret_cast<const short8*>(bsrc + 8);
    __syncthreads();
    short8 afr[4], bfr[4];
#pragma unroll
    for (int mi = 0; mi < 4; ++mi) afr[mi] = *reinterpret_cast<const short8*>(&a_lds[wr * 64 + mi * 16 + lm][g8]);
#pragma unroll
    for (int nj = 0; nj < 4; ++nj) bfr[nj] = *reinterpret_cast<const short8*>(&b_lds[wc * 64 + nj * 16 + lm][g8]);
#pragma unroll
    for (int mi = 0; mi < 4; ++mi)
#pragma unroll
      for (int nj = 0; nj < 4; ++nj)
        acc[mi][nj] = __builtin_amdgcn_mfma_f32_16x16x32_bf16(afr[mi], bfr[nj], acc[mi][nj], 0, 0, 0);
  }
  const int g4 = (lane >> 4) << 2;
#pragma unroll
  for (int mi = 0; mi < 4; ++mi)
#pragma unroll
    for (int nj = 0; nj < 4; ++nj)
#pragma unroll
      for (int r = 0; r < 4; ++r) {
        const int row = bm * 128 + wr * 64 + mi * 16 + g4 + r;
        const int col = bn * 128 + wc * 64 + nj * 16 + lm;
        const float v = acc[mi][nj][r];
        if (MODE == 2) {
          ((float*)outp)[(size_t)row * DIM + col] = v;
        } else {
          const int b = row >> 11, t = row & 2047, hh = col >> 6, hd = col & 63;
          const size_t idx = (((size_t)b * NH + hh) * LS + t) * HD + hd;
          if (MODE == 0) {
            ((short*)outp)[idx] = f2bf(v);
          } else {
            ((float*)outp)[idx] = v;
            out_bf[idx] = f2bf(v);
          }
        }
      }
}

// ---- fused flash attention v5: swizzled LDS + K/V double-buffer, 1 barrier/tile ----
// 1 block = 64 q-rows of one (b,h); 4 waves, 16 q-rows each. grid = 1024.
__global__ __launch_bounds__(256, 3) void attn_kernel(const short* __restrict__ qw, const short* __restrict__ kbf,
                                                      const short* __restrict__ vbf, const float* __restrict__ pe,
                                                      const float* __restrict__ mask, short* __restrict__ aout) {
  __shared__ __align__(16) char k_raw[2 * 64 * 128];   // K tiles  [s][d], swizzled, double-buffered
  __shared__ __align__(16) char vt_raw[2 * 64 * 128];  // V^T tiles [d][s], swizzled, double-buffered
  __shared__ __align__(16) char p_raw[4 * 16 * 128];   // P per wave [t][s], swizzled
  __shared__ float sc_lds[4][16];
  __shared__ float l_lds[4][16];
  const int bid = blockIdx.x;
  const int b = bid & 1;
  const int qt = (bid >> 1) & 31;
  const int h = (bid >> 6) & 15;
  const int bh = b * NH + h;
  const int tid = threadIdx.x, lane = tid & 63, w = tid >> 6;
  const int qbase = qt * 64 + w * 16;
  const int lm = lane & 15, g = lane >> 4, g16 = g << 4, g4 = g << 2;
  constexpr float L2E = 1.4426950408889634f;

  short8 qfr[2];
#pragma unroll
  for (int kk = 0; kk < 2; ++kk)
    qfr[kk] = *reinterpret_cast<const short8*>(qw + ((size_t)bh * LT + qbase + lm) * HD + kk * 32 + (g << 3));

  float m_run = -1e30f, l_run = 0.f;
  f32x4 acc_o[4];
#pragma unroll
  for (int dj = 0; dj < 4; ++dj) acc_o[dj] = (f32x4){0.f, 0.f, 0.f, 0.f};

  const int t_lane = qbase + lm;
  const float* pe_row = pe + (size_t)h * LT * LS + (size_t)t_lane * LS;
  const float* mask_row = mask + (size_t)t_lane * LS;

  const int srow = tid >> 2, scol0 = (tid & 3) << 4;  // K staging: 4 lanes per row
  const int vs2 = (lane & 31) << 1;                   // V staging rows
  const int vd0 = (w << 4) + ((lane >> 5) << 3);      // V staging d-slab
  const int kb = scol0 * 2;

  // staged K/V registers (two sets, alternating)
  short8 kA0, kA1, vA0, vA1;
  short8 kB0, kB1, vB0, vB1;

#define LOAD_ST(S0, K0, K1, V0, V1)                                   \
  {                                                                   \
    const short* ksrc = kbf + ((size_t)bh * LS + (S0) + srow) * HD + scol0; \
    K0 = *reinterpret_cast<const short8*>(ksrc);                      \
    K1 = *reinterpret_cast<const short8*>(ksrc + 8);                  \
    const short* vsrc = vbf + ((size_t)bh * LS + (S0) + vs2) * HD + vd0;    \
    V0 = *reinterpret_cast<const short8*>(vsrc);                      \
    V1 = *reinterpret_cast<const short8*>(vsrc + HD);                 \
  }

#define WRITE_ST(BUF, K0, K1, V0, V1)                                                   \
  {                                                                                     \
    char* kr = k_raw + (BUF)*8192;                                                      \
    *reinterpret_cast<short8*>(kr + swz(srow, kb)) = K0;                                \
    *reinterpret_cast<short8*>(kr + swz(srow, kb + 16)) = K1;                           \
    char* vr = vt_raw + (BUF)*8192;                                                     \
    _Pragma("unroll") for (int j = 0; j < 8; ++j) {                                     \
      short2v pr = {V0[j], V1[j]};                                                      \
      *reinterpret_cast<short2v*>(vr + swz(vd0 + j, vs2 * 2)) = pr;                     \
    }                                                                                   \
  }

  // prologue: stage tile 0 into buf 0; issue loads for tile 1 into set B
  LOAD_ST(0, kA0, kA1, vA0, vA1);
  WRITE_ST(0, kA0, kA1, vA0, vA1);
  LOAD_ST(64, kB0, kB1, vB0, vB1);

// TILE body: BUFR has tile S0; set {KW*,VW*} holds tile S0+64 (write into BUFW);
// load tile S0+128 into {KL*,VL*}.
#define TILE(S0, BUFR, BUFW, KW0, KW1, VW0, VW1, KL0, KL1, VL0, VL1)                                   \
  {                                                                                                    \
    __syncthreads();                                                                                   \
    f32x4 pv4[4], mv4[4];                                                                              \
    _Pragma("unroll") for (int nj = 0; nj < 4; ++nj) {                                                 \
      const int sn = (S0) + nj * 16 + g4;                                                              \
      pv4[nj] = *reinterpret_cast<const f32x4*>(pe_row + sn);                                          \
      mv4[nj] = *reinterpret_cast<const f32x4*>(mask_row + sn);                                        \
    }                                                                                                  \
    if ((S0) + 128 < LS) LOAD_ST((S0) + 128, KL0, KL1, VL0, VL1);                                      \
    f32x4 accs[4];                                                                                     \
    _Pragma("unroll") for (int nj = 0; nj < 4; ++nj) {                                                 \
      accs[nj] = (f32x4){0.f, 0.f, 0.f, 0.f};                                                          \
      _Pragma("unroll") for (int kk = 0; kk < 2; ++kk) {                                               \
        const short8 kfr =                                                                             \
            *reinterpret_cast<const short8*>(k_raw + (BUFR)*8192 + swz(nj * 16 + lm, kk * 64 + g16));  \
        accs[nj] = __builtin_amdgcn_mfma_f32_16x16x32_bf16(kfr, qfr[kk], accs[nj], 0, 0, 0);           \
      }                                                                                                \
    }                                                                                                  \
    _Pragma("unroll") for (int nj = 0; nj < 4; ++nj)                                                   \
        _Pragma("unroll") for (int r = 0; r < 4; ++r) accs[nj][r] =                                    \
            fmaf(accs[nj][r], 0.125f, pv4[nj][r] + mv4[nj][r]);                                        \
    float mx = accs[0][0];                                                                             \
    _Pragma("unroll") for (int nj = 0; nj < 4; ++nj)                                                   \
        _Pragma("unroll") for (int r = 0; r < 4; ++r) mx = fmaxf(mx, accs[nj][r]);                     \
    mx = fmaxf(mx, __shfl_xor(mx, 16));                                                                \
    mx = fmaxf(mx, __shfl_xor(mx, 32));                                                                \
    const float mnew = fmaxf(m_run, mx);                                                               \
    const float nm = mnew * L2E;                                                                       \
    float rs = 0.f;                                                                                    \
    _Pragma("unroll") for (int nj = 0; nj < 4; ++nj) _Pragma("unroll") for (int r = 0; r < 4; ++r) {   \
      const float p = exp2f(fmaf(accs[nj][r], L2E, -nm));                                              \
      accs[nj][r] = p;                                                                                 \
      rs += p;                                                                                         \
    }                                                                                                  \
    rs += __shfl_xor(rs, 16);                                                                          \
    rs += __shfl_xor(rs, 32);                                                                          \
    const float sc = exp2f(fmaf(m_run, L2E, -nm));                                                     \
    l_run = l_run * sc + rs;                                                                           \
    m_run = mnew;                                                                                      \
    _Pragma("unroll") for (int nj = 0; nj < 4; ++nj) {                                                 \
      short4v pk = {f2bf(accs[nj][0]), f2bf(accs[nj][1]), f2bf(accs[nj][2]), f2bf(accs[nj][3])};       \
      *reinterpret_cast<short4v*>(p_raw + (w << 11) + swz(lm, nj * 32 + g * 8)) = pk;                  \
    }                                                                                                  \
    if (g == 0) sc_lds[w][lm] = sc;                                                                    \
    const f32x4 sc4 = *reinterpret_cast<const f32x4*>(&sc_lds[w][g4]);                                 \
    _Pragma("unroll") for (int dj = 0; dj < 4; ++dj)                                                   \
        _Pragma("unroll") for (int r = 0; r < 4; ++r) acc_o[dj][r] *= sc4[r];                          \
    _Pragma("unroll") for (int kk = 0; kk < 2; ++kk) {                                                 \
      const short8 pfr = *reinterpret_cast<const short8*>(p_raw + (w << 11) + swz(lm, kk * 64 + g16)); \
      _Pragma("unroll") for (int dj = 0; dj < 4; ++dj) {                                               \
        const short8 vfr =                                                                             \
            *reinterpret_cast<const short8*>(vt_raw + (BUFR)*8192 + swz(dj * 16 + lm, kk * 64 + g16)); \
        acc_o[dj] = __builtin_amdgcn_mfma_f32_16x16x32_bf16(pfr, vfr, acc_o[dj], 0, 0, 0);             \
      }                                                                                                \
    }                                                                                                  \
    if ((S0) + 64 < LS) WRITE_ST(BUFW, KW0, KW1, VW0, VW1);                                            \
  }

  for (int tt = 0; tt < LS; tt += 128) {
    // even tile: read buf0, write set-B (tile tt+64) into buf1, load tt+128 into set-A
    TILE(tt, 0, 1, kB0, kB1, vB0, vB1, kA0, kA1, vA0, vA1);
    // odd tile: read buf1, write set-A (tile tt+128) into buf0, load tt+192 into set-B
    TILE(tt + 64, 1, 0, kA0, kA1, vA0, vA1, kB0, kB1, vB0, vB1);
  }
#undef TILE
#undef LOAD_ST
#undef WRITE_ST

  // epilogue: redistribute 1/l, write bf16 score_cat layout [B, LT, H*HD]
  if (g == 0) l_lds[w][lm] = l_run;
  const f32x4 l4 = *reinterpret_cast<const f32x4*>(&l_lds[w][g4]);
#pragma unroll
  for (int r = 0; r < 4; ++r) {
    const float inv = 1.f / l4[r];
    const int t = qbase + g4 + r;
#pragma unroll
    for (int dj = 0; dj < 4; ++dj) {
      const int d = dj * 16 + lm;
      aout[((size_t)b * LT + t) * DIM + h * HD + d] = f2bf(acc_o[dj][r] * inv);
    }
  }
}

extern "C" void kernel_launch(void* const* d_in, const int* in_sizes, int n_in, void* d_out, int out_size,
                              void* d_ws, size_t ws_size, hipStream_t stream) {
  (void)in_sizes;
  (void)n_in;
  (void)out_size;
  (void)ws_size;
  const float* x = (const float*)d_in[0];
  const float* memory = (const float*)d_in[1];
  const float* pe = (const float*)d_in[2];
  const float* mask = (const float*)d_in[3];
  const float* Wq = (const float*)d_in[4];
  const float* Wk = (const float*)d_in[5];
  const float* Wv = (const float*)d_in[6];
  const float* Wo = (const float*)d_in[7];
  float* outp = (float*)d_out;
  float* k_out = outp + (size_t)NB * NH * LS * HD;
  float* v_out = k_out + (size_t)NB * NH * LS * HD;
  char* ws = (char*)d_ws;
  short* q_ws = (short*)ws;                      //  8 MiB: Q bf16 [B,H,LT,HD]
  short* attn_ws = (short*)(ws + (8u << 20));    //  8 MiB: attn out bf16 [B,LT,D]
  short* wt = (short*)(ws + (16u << 20));        //  8 MiB: 4x Wt bf16 [N][K]
  short* k_bf = (short*)(ws + (24u << 20));      //  8 MiB: K bf16 [B,H,LS,HD]
  short* v_bf = (short*)(ws + (32u << 20));      //  8 MiB: V bf16 [B,H,LS,HD]

  wt_kernel<<<dim3(1024), dim3(256), 0, stream>>>(Wq, Wk, Wv, Wo, wt);
  gemm_kernel<0><<<dim3(256), dim3(256), 0, stream>>>(x, wt, (void*)q_ws, nullptr);
  gemm_kernel<1><<<dim3(256), dim3(256), 0, stream>>>(memory, wt + (1u << 20), (void*)k_out, k_bf);
  gemm_kernel<1><<<dim3(256), dim3(256), 0, stream>>>(memory, wt + (2u << 20), (void*)v_out, v_bf);
  attn_kernel<<<dim3(1024), dim3(256), 0, stream>>>(q_ws, k_bf, v_bf, pe, mask, attn_ws);
  gemm_kernel<2><<<dim3(256), dim3(256), 0, stream>>>(attn_ws, wt + (3u << 20), (void*)outp, nullptr);
}

// Round 6
// 253.321 us; speedup vs baseline: 1.4981x; 1.4981x over previous
//
#include <hip/hip_runtime.h>
#include <hip/hip_bf16.h>
#include <stdint.h>

#define NB 2
#define NH 16
#define LT 2048
#define LS 2048
#define DIM 1024
#define HD 64

typedef __attribute__((ext_vector_type(4))) float f32x4;
typedef __attribute__((ext_vector_type(8))) short short8;
typedef __attribute__((ext_vector_type(4))) short short4v;

__device__ __forceinline__ short f2bf(float f) {
  __hip_bfloat16 h = __float2bfloat16(f);
  return *reinterpret_cast<short*>(&h);
}

// async global->LDS, 16B per lane; LDS dest = wave-uniform base + lane*16
__device__ __forceinline__ void gl_lds16(const short* g, short* l) {
  __builtin_amdgcn_global_load_lds((const __attribute__((address_space(1))) void*)g,
                                   (__attribute__((address_space(3))) void*)l, 16, 0, 0);
}

// ---- prep: weight transpose+cast (bid<1024) + x/memory fp32->bf16 (bid>=1024) ----
__global__ __launch_bounds__(256) void prep_kernel(const float* __restrict__ x, const float* __restrict__ memory,
                                                   const float* __restrict__ Wq, const float* __restrict__ Wk,
                                                   const float* __restrict__ Wv, const float* __restrict__ Wo,
                                                   short* __restrict__ wt, short* __restrict__ xbf,
                                                   short* __restrict__ membf) {
  __shared__ float tile[64][68];
  const int bid = blockIdx.x;
  const int tid = threadIdx.x;
  if (bid < 1024) {
    const int widx = bid >> 8;
    const int rem = bid & 255;
    const int kt = rem >> 4, nt = rem & 15;
    const float* W = (widx == 0) ? Wq : (widx == 1) ? Wk : (widx == 2) ? Wv : Wo;
    {
      const int r = tid >> 2, c0 = (tid & 3) << 4;
      const float* src = W + (size_t)(kt * 64 + r) * DIM + nt * 64 + c0;
#pragma unroll
      for (int j = 0; j < 4; ++j)
        *reinterpret_cast<f32x4*>(&tile[r][c0 + 4 * j]) = *reinterpret_cast<const f32x4*>(src + 4 * j);
    }
    __syncthreads();
    {
      const int n = tid >> 2, k0 = (tid & 3) << 4;
      short outv[16];
#pragma unroll
      for (int j = 0; j < 16; ++j) outv[j] = f2bf(tile[k0 + j][n]);
      short* dst = wt + (size_t)widx * DIM * DIM + (size_t)(nt * 64 + n) * DIM + kt * 64 + k0;
      *reinterpret_cast<short8*>(dst) = *reinterpret_cast<short8*>(&outv[0]);
      *reinterpret_cast<short8*>(dst + 8) = *reinterpret_cast<short8*>(&outv[8]);
    }
  } else {
    const int cid = bid - 1024;
    const float* src = (cid < 1024) ? x : memory;
    short* dst = (cid < 1024) ? xbf : membf;
    const size_t base = (size_t)(cid & 1023) * 4096 + (size_t)tid * 16;
    const float* s = src + base;
    const f32x4 f0 = *reinterpret_cast<const f32x4*>(s);
    const f32x4 f1 = *reinterpret_cast<const f32x4*>(s + 4);
    const f32x4 f2 = *reinterpret_cast<const f32x4*>(s + 8);
    const f32x4 f3 = *reinterpret_cast<const f32x4*>(s + 12);
    short8 o0, o1;
#pragma unroll
    for (int j = 0; j < 4; ++j) {
      o0[j] = f2bf(f0[j]);
      o0[4 + j] = f2bf(f1[j]);
      o1[j] = f2bf(f2[j]);
      o1[4 + j] = f2bf(f3[j]);
    }
    *reinterpret_cast<short8*>(dst + base) = o0;
    *reinterpret_cast<short8*>(dst + base + 8) = o1;
  }
}

// ---- shared GEMM main loop: C[TM x 128] tile, BK=64, global_load_lds staging,
// LDS chunk-swizzled via pre-swizzled global source (chunk ^= row&7). ----
template <int TM, int MF>
__device__ __forceinline__ void mm_loop(const short* __restrict__ A, const short* __restrict__ Bt, short* a_lds,
                                        short* b_lds, int bm, int bn, int w, int lane, f32x4 (&acc)[MF][4]) {
  const int lm = lane & 15, g = lane >> 4;
  const int wr = w >> 1, wc = w & 1;
  const int lr8 = lane >> 3;                 // row within 8-row wave-write
  const int gch = (lane & 7) ^ (lr8 & 7);    // pre-swizzled source chunk (16B units)
  const short* Aw = A + (size_t)(bm * TM + w * 8 + lr8) * 1024 + gch * 8;
  const short* Bw = Bt + (size_t)(bn * 128 + w * 8 + lr8) * 1024 + gch * 8;
  short* al = a_lds + w * 512;  // wave-uniform LDS bases
  short* bl = b_lds + w * 512;
  const int axor = lm & 7;
  constexpr int JA = TM / 32;

  for (int k0 = 0; k0 < 1024; k0 += 64) {
    __syncthreads();
#pragma unroll
    for (int j = 0; j < JA; ++j) gl_lds16(Aw + (size_t)j * 32 * 1024 + k0, al + j * 2048);
#pragma unroll
    for (int j = 0; j < 4; ++j) gl_lds16(Bw + (size_t)j * 32 * 1024 + k0, bl + j * 2048);
    __syncthreads();  // compiler drains vmcnt before barrier -> tiles ready
    short8 afr[MF][2], bfr[4][2];
#pragma unroll
    for (int mi = 0; mi < MF; ++mi)
#pragma unroll
      for (int kk = 0; kk < 2; ++kk)
        afr[mi][kk] = *reinterpret_cast<const short8*>(
            &a_lds[(wr * (TM / 2) + mi * 16 + lm) * 64 + (((kk << 2) + g) ^ axor) * 8]);
#pragma unroll
    for (int nj = 0; nj < 4; ++nj)
#pragma unroll
      for (int kk = 0; kk < 2; ++kk)
        bfr[nj][kk] = *reinterpret_cast<const short8*>(
            &b_lds[(wc * 64 + nj * 16 + lm) * 64 + (((kk << 2) + g) ^ axor) * 8]);
#pragma unroll
    for (int mi = 0; mi < MF; ++mi)
#pragma unroll
      for (int nj = 0; nj < 4; ++nj)
#pragma unroll
        for (int kk = 0; kk < 2; ++kk)
          acc[mi][nj] = __builtin_amdgcn_mfma_f32_16x16x32_bf16(afr[mi][kk], bfr[nj][kk], acc[mi][nj], 0, 0, 0);
  }
}

// ---- merged Q/K/V projection GEMM: grid 768 (seg = Q/K/V), 128x128 tiles ----
__global__ __launch_bounds__(256, 3) void qkv_gemm(const short* __restrict__ xbf, const short* __restrict__ membf,
                                                   const short* __restrict__ wt, short* __restrict__ q_ws,
                                                   float* __restrict__ k_out, short* __restrict__ k_bf,
                                                   float* __restrict__ v_out, short* __restrict__ v_bf) {
  __shared__ short a_lds[128 * 64];
  __shared__ short b_lds[128 * 64];
  const int bid = blockIdx.x;
  const int seg = bid >> 8, rem = bid & 255;
  const int bm = rem & 31, bn = rem >> 5;
  const int tid = threadIdx.x, lane = tid & 63, w = tid >> 6;
  const short* A = (seg == 0) ? xbf : membf;
  const short* B = wt + ((size_t)seg << 20);
  f32x4 acc[4][4];
#pragma unroll
  for (int i = 0; i < 4; ++i)
#pragma unroll
    for (int j = 0; j < 4; ++j) acc[i][j] = (f32x4){0.f, 0.f, 0.f, 0.f};
  mm_loop<128, 4>(A, B, a_lds, b_lds, bm, bn, w, lane, acc);

  const int lm = lane & 15, g4 = (lane >> 4) << 2;
  const int wr = w >> 1, wc = w & 1;
#pragma unroll
  for (int mi = 0; mi < 4; ++mi)
#pragma unroll
    for (int nj = 0; nj < 4; ++nj)
#pragma unroll
      for (int r = 0; r < 4; ++r) {
        const int row = bm * 128 + wr * 64 + mi * 16 + g4 + r;
        const int col = bn * 128 + wc * 64 + nj * 16 + lm;
        const float v = acc[mi][nj][r];
        const int b = row >> 11, t = row & 2047, hh = col >> 6, hd = col & 63;
        const size_t idx = (((size_t)b * NH + hh) * LS + t) * HD + hd;
        if (seg == 0) {
          q_ws[idx] = f2bf(v);
        } else if (seg == 1) {
          k_out[idx] = v;
          k_bf[idx] = f2bf(v);
        } else {
          v_out[idx] = v;
          v_bf[idx] = f2bf(v);
        }
      }
}

// ---- output projection GEMM: 64x128 tiles, grid 512 (2 blocks/CU) ----
__global__ __launch_bounds__(256, 3) void o_gemm(const short* __restrict__ attn_bf, const short* __restrict__ wto,
                                                 float* __restrict__ outp) {
  __shared__ short a_lds[64 * 64];
  __shared__ short b_lds[128 * 64];
  const int bid = blockIdx.x;
  const int bm = bid & 63, bn = bid >> 6;
  const int tid = threadIdx.x, lane = tid & 63, w = tid >> 6;
  f32x4 acc[2][4];
#pragma unroll
  for (int i = 0; i < 2; ++i)
#pragma unroll
    for (int j = 0; j < 4; ++j) acc[i][j] = (f32x4){0.f, 0.f, 0.f, 0.f};
  mm_loop<64, 2>(attn_bf, wto, a_lds, b_lds, bm, bn, w, lane, acc);

  const int lm = lane & 15, g4 = (lane >> 4) << 2;
  const int wr = w >> 1, wc = w & 1;
#pragma unroll
  for (int mi = 0; mi < 2; ++mi)
#pragma unroll
    for (int nj = 0; nj < 4; ++nj)
#pragma unroll
      for (int r = 0; r < 4; ++r) {
        const int row = bm * 64 + wr * 32 + mi * 16 + g4 + r;
        const int col = bn * 128 + wc * 64 + nj * 16 + lm;
        outp[(size_t)row * DIM + col] = acc[mi][nj][r];
      }
}

// ---- fused flash attention (R3-verbatim, measured 206us): swapped-QK, coalesced pe/mask ----
__global__ __launch_bounds__(256, 4) void attn_kernel(const short* __restrict__ qw, const short* __restrict__ kbf,
                                                      const short* __restrict__ vbf, const float* __restrict__ pe,
                                                      const float* __restrict__ mask, short* __restrict__ aout) {
  __shared__ short k_lds[64][72];
  __shared__ short vt_lds[64][72];
  __shared__ short p_lds[4][16][72];
  __shared__ float sc_lds[4][16];
  __shared__ float l_lds[4][16];
  const int bid = blockIdx.x;
  const int b = bid & 1;
  const int qt = (bid >> 1) & 31;
  const int h = (bid >> 6) & 15;
  const int bh = b * NH + h;
  const int tid = threadIdx.x, lane = tid & 63, w = tid >> 6;
  const int qbase = qt * 64 + w * 16;
  const int lm = lane & 15, g = lane >> 4, g8 = g << 3, g4 = g << 2;
  constexpr float L2E = 1.4426950408889634f;

  typedef __attribute__((ext_vector_type(2))) short short2v;

  short8 qfr[2];
#pragma unroll
  for (int kk = 0; kk < 2; ++kk)
    qfr[kk] = *reinterpret_cast<const short8*>(qw + ((size_t)bh * LT + qbase + lm) * HD + kk * 32 + g8);

  float m_run = -1e30f, l_run = 0.f;
  f32x4 acc_o[4];
#pragma unroll
  for (int dj = 0; dj < 4; ++dj) acc_o[dj] = (f32x4){0.f, 0.f, 0.f, 0.f};

  const int t_lane = qbase + lm;
  const float* pe_row = pe + (size_t)h * LT * LS + (size_t)t_lane * LS;
  const float* mask_row = mask + (size_t)t_lane * LS;

  const int srow = tid >> 2, scol0 = (tid & 3) << 4;
  const int vs2 = (lane & 31) << 1;
  const int vd0 = (w << 4) + ((lane >> 5) << 3);

  for (int s0 = 0; s0 < LS; s0 += 64) {
    {
      const short* ksrc = kbf + ((size_t)bh * LS + s0 + srow) * HD + scol0;
      *reinterpret_cast<short8*>(&k_lds[srow][scol0]) = *reinterpret_cast<const short8*>(ksrc);
      *reinterpret_cast<short8*>(&k_lds[srow][scol0 + 8]) = *reinterpret_cast<const short8*>(ksrc + 8);
    }
    {
      const short* vsrc = vbf + ((size_t)bh * LS + s0 + vs2) * HD + vd0;
      const short8 va = *reinterpret_cast<const short8*>(vsrc);
      const short8 vb = *reinterpret_cast<const short8*>(vsrc + HD);
#pragma unroll
      for (int j = 0; j < 8; ++j) {
        short2v pr = {va[j], vb[j]};
        *reinterpret_cast<short2v*>(&vt_lds[vd0 + j][vs2]) = pr;
      }
    }
    __syncthreads();

    f32x4 pv4[4], mv4[4];
#pragma unroll
    for (int nj = 0; nj < 4; ++nj) {
      const int sbase = s0 + nj * 16 + g4;
      pv4[nj] = *reinterpret_cast<const f32x4*>(pe_row + sbase);
      mv4[nj] = *reinterpret_cast<const f32x4*>(mask_row + sbase);
    }

    f32x4 accs[4];
#pragma unroll
    for (int nj = 0; nj < 4; ++nj) {
      accs[nj] = (f32x4){0.f, 0.f, 0.f, 0.f};
#pragma unroll
      for (int kk = 0; kk < 2; ++kk) {
        const short8 kfr = *reinterpret_cast<const short8*>(&k_lds[nj * 16 + lm][kk * 32 + g8]);
        accs[nj] = __builtin_amdgcn_mfma_f32_16x16x32_bf16(kfr, qfr[kk], accs[nj], 0, 0, 0);
      }
    }

#pragma unroll
    for (int nj = 0; nj < 4; ++nj)
#pragma unroll
      for (int r = 0; r < 4; ++r) accs[nj][r] = fmaf(accs[nj][r], 0.125f, pv4[nj][r] + mv4[nj][r]);

    float mx = accs[0][0];
#pragma unroll
    for (int nj = 0; nj < 4; ++nj)
#pragma unroll
      for (int r = 0; r < 4; ++r) mx = fmaxf(mx, accs[nj][r]);
    mx = fmaxf(mx, __shfl_xor(mx, 16));
    mx = fmaxf(mx, __shfl_xor(mx, 32));
    const float mnew = fmaxf(m_run, mx);
    const float nm = mnew * L2E;
    float rs = 0.f;
#pragma unroll
    for (int nj = 0; nj < 4; ++nj)
#pragma unroll
      for (int r = 0; r < 4; ++r) {
        const float p = exp2f(fmaf(accs[nj][r], L2E, -nm));
        accs[nj][r] = p;
        rs += p;
      }
    rs += __shfl_xor(rs, 16);
    rs += __shfl_xor(rs, 32);
    const float sc = exp2f(fmaf(m_run, L2E, -nm));
    l_run = l_run * sc + rs;
    m_run = mnew;

#pragma unroll
    for (int nj = 0; nj < 4; ++nj) {
      short4v pk = {f2bf(accs[nj][0]), f2bf(accs[nj][1]), f2bf(accs[nj][2]), f2bf(accs[nj][3])};
      *reinterpret_cast<short4v*>(&p_lds[w][lm][nj * 16 + g4]) = pk;
    }
    if (g == 0) sc_lds[w][lm] = sc;
    const f32x4 sc4 = *reinterpret_cast<const f32x4*>(&sc_lds[w][g4]);
#pragma unroll
    for (int dj = 0; dj < 4; ++dj)
#pragma unroll
      for (int r = 0; r < 4; ++r) acc_o[dj][r] *= sc4[r];

#pragma unroll
    for (int kk = 0; kk < 2; ++kk) {
      const short8 pfr = *reinterpret_cast<const short8*>(&p_lds[w][lm][kk * 32 + g8]);
#pragma unroll
      for (int dj = 0; dj < 4; ++dj) {
        const short8 vfr = *reinterpret_cast<const short8*>(&vt_lds[dj * 16 + lm][kk * 32 + g8]);
        acc_o[dj] = __builtin_amdgcn_mfma_f32_16x16x32_bf16(pfr, vfr, acc_o[dj], 0, 0, 0);
      }
    }
    __syncthreads();
  }

  if (g == 0) l_lds[w][lm] = l_run;
  const f32x4 l4 = *reinterpret_cast<const f32x4*>(&l_lds[w][g4]);
#pragma unroll
  for (int r = 0; r < 4; ++r) {
    const float inv = 1.f / l4[r];
    const int t = qbase + g4 + r;
#pragma unroll
    for (int dj = 0; dj < 4; ++dj) {
      const int d = dj * 16 + lm;
      aout[((size_t)b * LT + t) * DIM + h * HD + d] = f2bf(acc_o[dj][r] * inv);
    }
  }
}

extern "C" void kernel_launch(void* const* d_in, const int* in_sizes, int n_in, void* d_out, int out_size,
                              void* d_ws, size_t ws_size, hipStream_t stream) {
  (void)in_sizes;
  (void)n_in;
  (void)out_size;
  (void)ws_size;
  const float* x = (const float*)d_in[0];
  const float* memory = (const float*)d_in[1];
  const float* pe = (const float*)d_in[2];
  const float* mask = (const float*)d_in[3];
  const float* Wq = (const float*)d_in[4];
  const float* Wk = (const float*)d_in[5];
  const float* Wv = (const float*)d_in[6];
  const float* Wo = (const float*)d_in[7];
  float* outp = (float*)d_out;
  float* k_out = outp + (size_t)NB * NH * LS * HD;
  float* v_out = k_out + (size_t)NB * NH * LS * HD;
  char* ws = (char*)d_ws;
  short* q_ws = (short*)ws;                      //  8 MiB: Q bf16 [B,H,LT,HD]
  short* attn_ws = (short*)(ws + (8u << 20));    //  8 MiB: attn out bf16 [B,LT,D]
  short* wt = (short*)(ws + (16u << 20));        //  8 MiB: 4x Wt bf16 [N][K]
  short* k_bf = (short*)(ws + (24u << 20));      //  8 MiB: K bf16 [B,H,LS,HD]
  short* v_bf = (short*)(ws + (32u << 20));      //  8 MiB: V bf16 [B,H,LS,HD]
  short* xbf = (short*)(ws + (40u << 20));       //  8 MiB: x bf16 [B*LT, D]
  short* membf = (short*)(ws + (48u << 20));     //  8 MiB: memory bf16 [B*LS, D]

  prep_kernel<<<dim3(3072), dim3(256), 0, stream>>>(x, memory, Wq, Wk, Wv, Wo, wt, xbf, membf);
  qkv_gemm<<<dim3(768), dim3(256), 0, stream>>>(xbf, membf, wt, q_ws, k_out, k_bf, v_out, v_bf);
  attn_kernel<<<dim3(1024), dim3(256), 0, stream>>>(q_ws, k_bf, v_bf, pe, mask, attn_ws);
  o_gemm<<<dim3(512), dim3(256), 0, stream>>>(attn_ws, wt + (3u << 20), outp);
}